// Round 8
// baseline (2096.820 us; speedup 1.0000x reference)
//
#include <hip/hip_runtime.h>
#include <hip/hip_bf16.h>

// Problem constants
#define S_LEN  1024
#define B_SZ   32
#define IN_DIM 3072
#define HID    256
#define NHEAD  16
#define HDIM   16
#define DFF    1024
#define NLAYER 4
#define NCLS   1623
#define EMB_D  10
#define MROWS  (S_LEN * B_SZ)   // 32768
#define QSTRIDE 52               // padded per-step qkvb stride (16B aligned)
#define CHUNK  32                // scan steps staged per LDS chunk

using bf16   = __hip_bfloat16;
using short8 = __attribute__((ext_vector_type(8))) short;
using f32x4  = __attribute__((ext_vector_type(4))) float;

#define GLOAD16(g, l) __builtin_amdgcn_global_load_lds(                        \
    (const __attribute__((address_space(1))) void*)(g),                        \
    (__attribute__((address_space(3))) void*)(l), 16, 0, 0)

// ---------------------------------------------------------------------------
// bf16 MFMA GEMM: C[M,N] = A[M,K]@W[N,K]^T.  BM=BN=128, BK=32, 256 thr/4 waves,
// each wave a 64x64 quadrant (4x4 frags of 16x16x32). K multiple of 32.
// W buffers padded to 128-multiple rows. FLAGS: 1 bias, 2 relu, 4 residual(fp32),
// 8 bf16-out, 16 permuted qkvb store (fp32, (b,h,s,52) layout).
// ---------------------------------------------------------------------------
template<int FLAGS>
__global__ __launch_bounds__(256) void mgemm(
    const bf16* __restrict__ A, const bf16* __restrict__ W,
    const float* __restrict__ bias, const float* R, void* C,
    int N, int K, int Wld)
{
    __shared__ bf16 sA[2][128 * 32];
    __shared__ bf16 sB[2][128 * 32];
    const int t    = threadIdx.x;
    const int lane = t & 63;
    const int wid  = t >> 6;
    const int wr   = wid >> 1, wc = wid & 1;
    const long bm  = (long)blockIdx.x * 128;
    const int  bn  = blockIdx.y * 128;
    const int  fr  = lane & 15;        // frag row/col
    const int  fg  = lane >> 4;        // k-group
    const int  row0 = t >> 2;          // staging row (0..63), +64 for 2nd issue
    const int  kq0  = (t & 3) << 3;    // staging k offset (elems)

    f32x4 acc[4][4];
#pragma unroll
    for (int m = 0; m < 4; ++m)
#pragma unroll
        for (int n = 0; n < 4; ++n)
#pragma unroll
            for (int r = 0; r < 4; ++r) acc[m][n][r] = 0.f;

    const int nkt = K >> 5;

    auto stage = [&](int buf, int kt) {
        const int k0 = kt << 5;
        GLOAD16(A + (bm + row0)      * (long)K   + k0 + kq0, &sA[buf][(t      ) * 8]);
        GLOAD16(A + (bm + row0 + 64) * (long)K   + k0 + kq0, &sA[buf][(t + 256) * 8]);
        GLOAD16(W + (long)(bn + row0)      * Wld + k0 + kq0, &sB[buf][(t      ) * 8]);
        GLOAD16(W + (long)(bn + row0 + 64) * Wld + k0 + kq0, &sB[buf][(t + 256) * 8]);
    };

    stage(0, 0);
    __syncthreads();
    for (int kt = 0; kt < nkt; ++kt) {
        const int cur = kt & 1;
        if (kt + 1 < nkt) stage(cur ^ 1, kt + 1);
        short8 af[4], bg[4];
#pragma unroll
        for (int m = 0; m < 4; ++m)
            af[m] = *(const short8*)&sA[cur][(wr * 64 + m * 16 + fr) * 32 + fg * 8];
#pragma unroll
        for (int n = 0; n < 4; ++n)
            bg[n] = *(const short8*)&sB[cur][(wc * 64 + n * 16 + fr) * 32 + fg * 8];
#pragma unroll
        for (int m = 0; m < 4; ++m)
#pragma unroll
            for (int n = 0; n < 4; ++n)
                acc[m][n] = __builtin_amdgcn_mfma_f32_16x16x32_bf16(
                    af[m], bg[n], acc[m][n], 0, 0, 0);
        __syncthreads();
    }

    // Epilogue. C/D layout (HW-verified): col = lane&15, row = (lane>>4)*4+reg.
    float bs[4];
#pragma unroll
    for (int n = 0; n < 4; ++n) {
        const int c = bn + wc * 64 + n * 16 + fr;
        bs[n] = ((FLAGS & 1) && c < N) ? bias[c] : 0.f;
    }
#pragma unroll
    for (int m = 0; m < 4; ++m) {
#pragma unroll
        for (int n = 0; n < 4; ++n) {
            const int c = bn + wc * 64 + n * 16 + fr;
            if (c < N) {
#pragma unroll
                for (int r = 0; r < 4; ++r) {
                    const long rw = bm + wr * 64 + m * 16 + fg * 4 + r;
                    float v = acc[m][n][r] + bs[n];
                    if (FLAGS & 2) v = fmaxf(v, 0.f);
                    if (FLAGS & 4) v += R[rw * N + c];
                    if (FLAGS & 16) {
                        const int s = (int)(rw >> 5), b = (int)(rw & 31);
                        const int hh = c / 49, cc = c - hh * 49;
                        ((float*)C)[((long)(b * 16 + hh) * 1024 + s) * QSTRIDE + cc] = v;
                    } else if (FLAGS & 8) {
                        ((bf16*)C)[rw * N + c] = __float2bfloat16(v);
                    } else {
                        ((float*)C)[rw * N + c] = v;
                    }
                }
            }
        }
    }
}

// ---------------------------------------------------------------------------
// fp32 -> bf16 bulk convert, count divisible by 8.
// ---------------------------------------------------------------------------
__global__ __launch_bounds__(256) void cvt8(const float* __restrict__ s,
                                            bf16* __restrict__ d, long n8)
{
    for (long i = (long)blockIdx.x * 256 + threadIdx.x; i < n8;
         i += (long)gridDim.x * 256) {
        const float4 a = ((const float4*)s)[i * 2];
        const float4 b = ((const float4*)s)[i * 2 + 1];
        alignas(16) bf16 t[8];
        t[0] = __float2bfloat16(a.x); t[1] = __float2bfloat16(a.y);
        t[2] = __float2bfloat16(a.z); t[3] = __float2bfloat16(a.w);
        t[4] = __float2bfloat16(b.x); t[5] = __float2bfloat16(b.y);
        t[6] = __float2bfloat16(b.z); t[7] = __float2bfloat16(b.w);
        ((short8*)d)[i] = *(const short8*)t;
    }
}

// ---------------------------------------------------------------------------
// fp32 [rows][cols] -> bf16 [prows][pcols], zero-padded.
// ---------------------------------------------------------------------------
__global__ __launch_bounds__(256) void cvtpad(const float* __restrict__ s,
                                              bf16* __restrict__ d,
                                              int rows, int cols, int prows, int pcols)
{
    const long tot = (long)prows * pcols;
    for (long i = (long)blockIdx.x * 256 + threadIdx.x; i < tot;
         i += (long)gridDim.x * 256) {
        const int r = (int)(i / pcols), c = (int)(i - (long)r * pcols);
        d[i] = (r < rows && c < cols) ? __float2bfloat16(s[(long)r * cols + c])
                                      : __float2bfloat16(0.f);
    }
}

// ---------------------------------------------------------------------------
// LayerNorm(256) -> bf16. One wave per row, 4 rows/block.
// ---------------------------------------------------------------------------
__global__ __launch_bounds__(256) void ln_b(
    const float* __restrict__ x, const float* __restrict__ g,
    const float* __restrict__ b, bf16* __restrict__ y)
{
    const int wave = threadIdx.x >> 6, lane = threadIdx.x & 63;
    const long row = (long)(blockIdx.x << 2) + wave;
    const float4 v = ((const float4*)(x + row * HID))[lane];
    float s = v.x + v.y + v.z + v.w;
#pragma unroll
    for (int m = 32; m; m >>= 1) s += __shfl_xor(s, m);
    const float mean = s * (1.f / 256.f);
    const float d0 = v.x - mean, d1 = v.y - mean, d2 = v.z - mean, d3 = v.w - mean;
    float ss = d0 * d0 + d1 * d1 + d2 * d2 + d3 * d3;
#pragma unroll
    for (int m = 32; m; m >>= 1) ss += __shfl_xor(ss, m);
    const float inv = rsqrtf(ss * (1.f / 256.f) + 1e-5f);
    const float4 gg = ((const float4*)g)[lane];
    const float4 bb = ((const float4*)b)[lane];
    alignas(8) bf16 t[4];
    t[0] = __float2bfloat16(fmaf(d0 * inv, gg.x, bb.x));
    t[1] = __float2bfloat16(fmaf(d1 * inv, gg.y, bb.y));
    t[2] = __float2bfloat16(fmaf(d2 * inv, gg.z, bb.z));
    t[3] = __float2bfloat16(fmaf(d3 * inv, gg.w, bb.w));
    *(ushort4*)((unsigned short*)y + row * HID + lane * 4) = *(const ushort4*)t;
}

// ---------------------------------------------------------------------------
// Concat: hcat[row] = [abuf[row] (256 bf16), bf16(emb[fb[row]]) (10), 0 (22)]
// ---------------------------------------------------------------------------
__global__ __launch_bounds__(64) void concat_b(
    const bf16* __restrict__ ab, const float* __restrict__ emb,
    const int* __restrict__ fb, bf16* __restrict__ hcat)
{
    const long row = blockIdx.x;
    const int lane = threadIdx.x;
    const ushort4 v = ((const ushort4*)(ab + row * HID))[lane];
    ((ushort4*)(hcat + row * 288))[lane] = v;
    if (lane < 32) {
        bf16 val = (lane < EMB_D)
            ? __float2bfloat16(emb[(long)fb[row] * EMB_D + lane])
            : __float2bfloat16(0.f);
        hcat[row * 288 + 256 + lane] = val;
    }
}

// 16-element dot of W-column (per-lane regs) with a broadcast row in 4 float4s
#define RED16(dst, M, r0, r1, r2, r3) do {                                     \
    float _ra = fmaf((M)[3],  (r0).w, fmaf((M)[2],  (r0).z, fmaf((M)[1],  (r0).y, (M)[0]  * (r0).x))); \
    float _rb = fmaf((M)[7],  (r1).w, fmaf((M)[6],  (r1).z, fmaf((M)[5],  (r1).y, (M)[4]  * (r1).x))); \
    float _rc = fmaf((M)[11], (r2).w, fmaf((M)[10], (r2).z, fmaf((M)[9],  (r2).y, (M)[8]  * (r2).x))); \
    float _rd = fmaf((M)[15], (r3).w, fmaf((M)[14], (r3).z, fmaf((M)[13], (r3).y, (M)[12] * (r3).x))); \
    dst = (_ra + _rb) + (_rc + _rd);                                           \
} while (0)

// ---------------------------------------------------------------------------
// Delta-rule scan v5: rank-1 lookahead decomposition.
//   b_{t+1} = W_t·k_{t+1} = g_{t+1} + dv_t·kkn_t,  g_{t+1}=W_{t-1}·k_{t+1}
//   o_t     = a_t + dv_t·kq_t,                     a_t    =W_{t-1}·q_t
// kq_t=k_t·q_t and kkn_t=k_t·k_{t+1} are precomputed in prep pass-2 (row slots
// [50],[51]); g/a are computed OFF the critical path with a full step of slack.
// Critical chain per step = 2 dependent fmaf. One wave per 4 chains
// (c=lane>>4, vi=lane&15); lane holds W[:,vi] (16 regs); no cross-lane ops.
// Chunks double-buffered in LDS via global_load_lds + counted vmcnt.
// ---------------------------------------------------------------------------
__global__ __launch_bounds__(64) void scan5(
    const float* __restrict__ qkvb, bf16* __restrict__ o)
{
    __shared__ float lds[2][4 * CHUNK * 52];   // 2 x 26624 B
    const int lane = threadIdx.x;
    const int c  = lane >> 4;        // chain within block
    const int vi = lane & 15;        // v column
    const int bh0 = blockIdx.x << 2; // 4 chains per block
    const int chain = bh0 + c;
    const int b = chain >> 4, hh = chain & 15;

    bf16* po = o + (long)b * HID + hh * HDIM + vi;

    // stage chunk ch into lds[buf]: 26 issues x 64 lanes x 16B
    auto stage = [&](int buf, int ch) {
#pragma unroll
        for (int i = 0; i < 26; ++i) {
            const int slot = i * 64 + lane;        // float4 slot in LDS
            const int row  = slot / 13;            // 0..127 = s_local*4 + cc
            const int f4   = slot - row * 13;
            const int cc   = row & 3, sl = row >> 2;
            const float* src = qkvb
                + (((long)(bh0 + cc) << 10) + ch * CHUNK + sl) * QSTRIDE + f4 * 4;
            GLOAD16(src, &lds[buf][i * 256]);
        }
    };

    float W[16];
#pragma unroll
    for (int j = 0; j < 16; ++j) W[j] = 0.f;

    stage(0, 0);
    asm volatile("s_waitcnt vmcnt(0)" ::: "memory");
    const int nch = S_LEN / CHUNK;
    for (int ch = 0; ch < nch; ++ch) {
        const int buf = ch & 1;
        // chunk ch's 26 loads are the oldest outstanding vmem ops; <=32 output
        // stores (newer) may stay in flight.
        asm volatile("s_waitcnt vmcnt(32)" ::: "memory");
        if (ch + 1 < nch) stage(buf ^ 1, ch + 1);   // lands during prep+rec

        float* base = lds[buf];
        // ---- prep pass-1: softmax q[0:16], k[16:32], sigmoid beta[48] ----
#pragma unroll
        for (int rr = 0; rr < 2; ++rr) {
            float* p = base + (rr * 64 + lane) * 52;
            float4 q[4], k[4];
#pragma unroll
            for (int i = 0; i < 4; ++i) {
                q[i] = *(float4*)(p + i * 4);
                k[i] = *(float4*)(p + 16 + i * 4);
            }
            float qm = -1e30f, km = -1e30f;
#pragma unroll
            for (int i = 0; i < 4; ++i) {
                qm = fmaxf(qm, fmaxf(fmaxf(q[i].x, q[i].y), fmaxf(q[i].z, q[i].w)));
                km = fmaxf(km, fmaxf(fmaxf(k[i].x, k[i].y), fmaxf(k[i].z, k[i].w)));
            }
            float qs = 0.f, ks = 0.f;
#pragma unroll
            for (int i = 0; i < 4; ++i) {
                q[i].x = __expf(q[i].x - qm); q[i].y = __expf(q[i].y - qm);
                q[i].z = __expf(q[i].z - qm); q[i].w = __expf(q[i].w - qm);
                qs += q[i].x + q[i].y + q[i].z + q[i].w;
                k[i].x = __expf(k[i].x - km); k[i].y = __expf(k[i].y - km);
                k[i].z = __expf(k[i].z - km); k[i].w = __expf(k[i].w - km);
                ks += k[i].x + k[i].y + k[i].z + k[i].w;
            }
            const float qi = 1.f / qs, ki = 1.f / ks;
#pragma unroll
            for (int i = 0; i < 4; ++i) {
                q[i].x *= qi; q[i].y *= qi; q[i].z *= qi; q[i].w *= qi;
                k[i].x *= ki; k[i].y *= ki; k[i].z *= ki; k[i].w *= ki;
                *(float4*)(p + i * 4) = q[i];
                *(float4*)(p + 16 + i * 4) = k[i];
            }
            p[48] = 1.f / (1.f + __expf(-p[48]));
        }
        asm volatile("s_waitcnt lgkmcnt(0)" ::: "memory");  // pass-1 visible

        // ---- prep pass-2: kq = k·q, kkn = k·k_next into row[50],[51] ----
#pragma unroll
        for (int rr = 0; rr < 2; ++rr) {
            const int r = rr * 64 + lane;
            float* p = base + r * 52;
            float4 q0 = *(float4*)(p),      q1 = *(float4*)(p + 4);
            float4 q2 = *(float4*)(p + 8),  q3 = *(float4*)(p + 12);
            float4 k0 = *(float4*)(p + 16), k1 = *(float4*)(p + 20);
            float4 k2 = *(float4*)(p + 24), k3 = *(float4*)(p + 28);
            float kq = ((k0.x*q0.x + k0.y*q0.y) + (k0.z*q0.z + k0.w*q0.w))
                     + ((k1.x*q1.x + k1.y*q1.y) + (k1.z*q1.z + k1.w*q1.w))
                     + ((k2.x*q2.x + k2.y*q2.y) + (k2.z*q2.z + k2.w*q2.w))
                     + ((k3.x*q3.x + k3.y*q3.y) + (k3.z*q3.z + k3.w*q3.w));
            float kkn = 0.f;
            if (r + 4 < 4 * CHUNK) {
                const float* pn = base + (r + 4) * 52;
                float4 n0 = *(const float4*)(pn + 16), n1 = *(const float4*)(pn + 20);
                float4 n2 = *(const float4*)(pn + 24), n3 = *(const float4*)(pn + 28);
                kkn = ((k0.x*n0.x + k0.y*n0.y) + (k0.z*n0.z + k0.w*n0.w))
                    + ((k1.x*n1.x + k1.y*n1.y) + (k1.z*n1.z + k1.w*n1.w))
                    + ((k2.x*n2.x + k2.y*n2.y) + (k2.z*n2.z + k2.w*n2.w))
                    + ((k3.x*n3.x + k3.y*n3.y) + (k3.z*n3.z + k3.w*n3.w));
            }
            float2 kk; kk.x = kq; kk.y = kkn;
            *(float2*)(p + 50) = kk;
        }
        asm volatile("s_waitcnt lgkmcnt(0)" ::: "memory");  // pass-2 visible

        // ---- recurrence: 2-fmaf critical path per step ----
        const int sg0 = ch * CHUNK;
        const float* r0 = base + c * 52;
        const float* r1 = base + (4 + c) * 52;
        float4 kc0 = *(const float4*)(r0 + 16), kc1 = *(const float4*)(r0 + 20);
        float4 kc2 = *(const float4*)(r0 + 24), kc3 = *(const float4*)(r0 + 28);
        float4 kn0 = *(const float4*)(r1 + 16), kn1 = *(const float4*)(r1 + 20);
        float4 kn2 = *(const float4*)(r1 + 24), kn3 = *(const float4*)(r1 + 28);
        float4 qc0 = *(const float4*)(r0),      qc1 = *(const float4*)(r0 + 4);
        float4 qc2 = *(const float4*)(r0 + 8),  qc3 = *(const float4*)(r0 + 12);
        float4 s0  = *(const float4*)(r0 + 48);            // β, pad, kq, kkn
        float vt = r0[32 + vi];
        float bt = s0.x, kqt = s0.z, kknt = s0.w;
        float g; RED16(g, W, kc0, kc1, kc2, kc3);          // W_{-1}·k_0
        float dvp = 0.f, kknp = 0.f;
#pragma unroll
        for (int sl = 0; sl < CHUNK; ++sl) {
            // critical chain
            const float bb = fmaf(dvp, kknp, g);
            const float mv = bt * vt;
            const float dv = fmaf(-bt, bb, mv);
            // prefetch (k at distance 2, q/scalars at distance 1)
            float4 kf0 = {}, kf1 = {}, kf2 = {}, kf3 = {};
            float4 qn0 = {}, qn1 = {}, qn2 = {}, qn3 = {}, sn = {};
            float vn = 0.f;
            if (sl + 2 < CHUNK) {
                const float* pf = base + ((sl + 2) * 4 + c) * 52;
                kf0 = *(const float4*)(pf + 16); kf1 = *(const float4*)(pf + 20);
                kf2 = *(const float4*)(pf + 24); kf3 = *(const float4*)(pf + 28);
            }
            if (sl + 1 < CHUNK) {
                const float* pn = base + ((sl + 1) * 4 + c) * 52;
                qn0 = *(const float4*)(pn);      qn1 = *(const float4*)(pn + 4);
                qn2 = *(const float4*)(pn + 8);  qn3 = *(const float4*)(pn + 12);
                sn  = *(const float4*)(pn + 48);
                vn  = pn[32 + vi];
            }
            // off-critical computes on OLD W (before this step's update)
            float gn = 0.f;
            if (sl + 1 < CHUNK) RED16(gn, W, kn0, kn1, kn2, kn3);
            float a; RED16(a, W, qc0, qc1, qc2, qc3);
            // W update (needs dv; independent of gn/a)
            W[0]  = fmaf(kc0.x, dv, W[0]);  W[1]  = fmaf(kc0.y, dv, W[1]);
            W[2]  = fmaf(kc0.z, dv, W[2]);  W[3]  = fmaf(kc0.w, dv, W[3]);
            W[4]  = fmaf(kc1.x, dv, W[4]);  W[5]  = fmaf(kc1.y, dv, W[5]);
            W[6]  = fmaf(kc1.z, dv, W[6]);  W[7]  = fmaf(kc1.w, dv, W[7]);
            W[8]  = fmaf(kc2.x, dv, W[8]);  W[9]  = fmaf(kc2.y, dv, W[9]);
            W[10] = fmaf(kc2.z, dv, W[10]); W[11] = fmaf(kc2.w, dv, W[11]);
            W[12] = fmaf(kc3.x, dv, W[12]); W[13] = fmaf(kc3.y, dv, W[13]);
            W[14] = fmaf(kc3.z, dv, W[14]); W[15] = fmaf(kc3.w, dv, W[15]);
            // output: o_t = a + dv*kq_t
            const float ov = fmaf(dv, kqt, a);
            po[(long)(sg0 + sl) * (B_SZ * HID)] = __float2bfloat16(ov);
            // rotate
            g = gn; dvp = dv; kknp = kknt;
            if (sl + 1 < CHUNK) {
                kc0 = kn0; kc1 = kn1; kc2 = kn2; kc3 = kn3;
                qc0 = qn0; qc1 = qn1; qc2 = qn2; qc3 = qn3;
                bt = sn.x; kqt = sn.z; kknt = sn.w; vt = vn;
            }
            if (sl + 2 < CHUNK) { kn0 = kf0; kn1 = kf1; kn2 = kf2; kn3 = kf3; }
        }
    }
}

// ---------------------------------------------------------------------------
extern "C" void kernel_launch(void* const* d_in, const int* in_sizes, int n_in,
                              void* d_out, int out_size, void* d_ws, size_t ws_size,
                              hipStream_t stream)
{
    const float* x      = (const float*)d_in[0];
    const int*   fb     = (const int*)  d_in[1];
    const float* fc1_w  = (const float*)d_in[2];
    const float* fc1_b  = (const float*)d_in[3];
    const float* emb    = (const float*)d_in[4];
    const float* proj_w = (const float*)d_in[5];
    const float* proj_b = (const float*)d_in[6];
    const float* ln1_g  = (const float*)d_in[7];
    const float* ln1_b  = (const float*)d_in[8];
    const float* slow_w = (const float*)d_in[9];
    const float* out_w  = (const float*)d_in[10];
    const float* ln2_g  = (const float*)d_in[11];
    const float* ln2_b  = (const float*)d_in[12];
    const float* ff1_w  = (const float*)d_in[13];
    const float* ff1_b  = (const float*)d_in[14];
    const float* ff2_w  = (const float*)d_in[15];
    const float* ff2_b  = (const float*)d_in[16];
    const float* outl_w = (const float*)d_in[17];
    const float* outl_b = (const float*)d_in[18];

    // ---- workspace layout (59.5 MB) ----
    char* wp = (char*)d_ws;
    float* h    = (float*)wp;                 wp += (size_t)MROWS * HID * 4;   // 33.5MB
    bf16*  abuf = (bf16*)wp;                  wp += (size_t)MROWS * HID * 2;   // 16.8MB
    bf16*  fc1b = (bf16*)wp;                  wp += (size_t)HID * IN_DIM * 2;
    bf16*  projb= (bf16*)wp;                  wp += (size_t)HID * 288 * 2;
    bf16*  slowb= (bf16*)wp;                  wp += (size_t)NLAYER * 896 * HID * 2;
    bf16*  outwb= (bf16*)wp;                  wp += (size_t)NLAYER * HID * HID * 2;
    bf16*  ff1b = (bf16*)wp;                  wp += (size_t)NLAYER * DFF * HID * 2;
    bf16*  ff2b = (bf16*)wp;                  wp += (size_t)NLAYER * HID * DFF * 2;
    bf16*  outlb= (bf16*)wp;                  wp += (size_t)1664 * HID * 2;

    // ---- d_out scratch (212.9 MB), sequentially reused ----
    bf16*  xb   = (bf16*)d_out;               // 201.3MB, dead after fc1
    bf16*  hcat = (bf16*)d_out;               // 18.9MB, dead after proj
    float* qkvb = (float*)d_out;              // 109.1MB, dead after scan
    bf16*  hff  = (bf16*)d_out;               // 67.1MB, dead after ff2

    const dim3 blk(256);

    // ---- weight/input conversions (re-done every launch; deterministic) ----
    cvt8<<<dim3(4096), blk, 0, stream>>>(x, xb, (long)MROWS * IN_DIM / 8);
    cvt8<<<dim3(384),  blk, 0, stream>>>(fc1_w, fc1b, (long)HID * IN_DIM / 8);
    cvtpad<<<dim3(288), blk, 0, stream>>>(proj_w, projb, HID, HID + EMB_D, HID, 288);
    for (int l = 0; l < NLAYER; ++l)
        cvtpad<<<dim3(896), blk, 0, stream>>>(slow_w + (size_t)l * 784 * HID,
                                              slowb + (size_t)l * 896 * HID,
                                              784, HID, 896, HID);
    cvt8<<<dim3(128), blk, 0, stream>>>(out_w, outwb, (long)NLAYER * HID * HID / 8);
    cvt8<<<dim3(512), blk, 0, stream>>>(ff1_w, ff1b, (long)NLAYER * DFF * HID / 8);
    cvt8<<<dim3(512), blk, 0, stream>>>(ff2_w, ff2b, (long)NLAYER * HID * DFF / 8);
    cvtpad<<<dim3(1664), blk, 0, stream>>>(outl_w, outlb, NCLS, HID, 1664, HID);

    // fc1: abuf = bf16(x @ fc1_w^T + b)    N=256 K=3072
    mgemm<9><<<dim3(256, 2), blk, 0, stream>>>(xb, fc1b, fc1_b, nullptr, abuf,
                                               HID, IN_DIM, IN_DIM);
    // hcat = [abuf, emb[fb], 0-pad]  (K padded to 288)
    concat_b<<<dim3(MROWS), dim3(64), 0, stream>>>(abuf, emb, fb, hcat);
    // proj: h = hcat @ proj_w^T + b        N=256 K=288(266+pad)
    mgemm<1><<<dim3(256, 2), blk, 0, stream>>>(hcat, projb, proj_b, nullptr, h,
                                               HID, 288, 288);

    for (int l = 0; l < NLAYER; ++l) {
        ln_b<<<dim3(MROWS / 4), blk, 0, stream>>>(h, ln1_g + l * HID, ln1_b + l * HID, abuf);
        // qkvb (permuted (b,h,s,52) fp32, RAW — softmax fused into scan5)
        mgemm<16><<<dim3(256, 7), blk, 0, stream>>>(abuf, slowb + (size_t)l * 896 * HID,
                                                    nullptr, nullptr, qkvb, 784, HID, HID);
        scan5<<<dim3(B_SZ * NHEAD / 4), dim3(64), 0, stream>>>(qkvb, abuf);
        // h += o @ out_w^T                  N=256 K=256
        mgemm<4><<<dim3(256, 2), blk, 0, stream>>>(abuf, outwb + (size_t)l * HID * HID,
                                                   nullptr, h, h, HID, HID, HID);
        ln_b<<<dim3(MROWS / 4), blk, 0, stream>>>(h, ln2_g + l * HID, ln2_b + l * HID, abuf);
        // hff = bf16(relu(y @ ff1^T + b1))  N=1024 K=256
        mgemm<11><<<dim3(256, 8), blk, 0, stream>>>(abuf, ff1b + (size_t)l * DFF * HID,
                                                    ff1_b + l * DFF, nullptr, hff,
                                                    DFF, HID, HID);
        // h += hff @ ff2^T + b2             N=256 K=1024
        mgemm<5><<<dim3(256, 2), blk, 0, stream>>>(hff, ff2b + (size_t)l * HID * DFF,
                                                   ff2_b + l * HID, h, h, HID, DFF, DFF);
    }
    // final: abuf = bf16(h); out = abuf @ outl_w^T + b  (fp32, N=1623 K=256)
    cvt8<<<dim3(1024), blk, 0, stream>>>(h, abuf, (long)MROWS * HID / 8);
    mgemm<1><<<dim3(256, 13), blk, 0, stream>>>(abuf, outlb, outl_b, nullptr, d_out,
                                                NCLS, HID, HID);
}

// Round 9
// 2010.567 us; speedup vs baseline: 1.0429x; 1.0429x over previous
//
#include <hip/hip_runtime.h>
#include <hip/hip_bf16.h>

// Problem constants
#define S_LEN  1024
#define B_SZ   32
#define IN_DIM 3072
#define HID    256
#define NHEAD  16
#define HDIM   16
#define DFF    1024
#define NLAYER 4
#define NCLS   1623
#define EMB_D  10
#define MROWS  (S_LEN * B_SZ)   // 32768
#define QSTRIDE 52               // padded per-step qkvb stride (16B aligned)
#define CHUNK  32                // scan steps staged per LDS chunk
#define BUFF   (4 * CHUNK * 52)  // floats per scan LDS buffer (6656)

using bf16   = __hip_bfloat16;
using short8 = __attribute__((ext_vector_type(8))) short;
using f32x4  = __attribute__((ext_vector_type(4))) float;

#define GLOAD16(g, l) __builtin_amdgcn_global_load_lds(                        \
    (const __attribute__((address_space(1))) void*)(g),                        \
    (__attribute__((address_space(3))) void*)(l), 16, 0, 0)

// ---------------------------------------------------------------------------
// bf16 MFMA GEMM: C[M,N] = A[M,K]@W[N,K]^T.  BM=BN=128, BK=32, 256 thr/4 waves,
// each wave a 64x64 quadrant (4x4 frags of 16x16x32). K multiple of 32.
// W buffers padded to 128-multiple rows. FLAGS: 1 bias, 2 relu, 4 residual(fp32),
// 8 bf16-out, 16 permuted qkvb store (fp32, (b,h,s,52) layout).
// ---------------------------------------------------------------------------
template<int FLAGS>
__global__ __launch_bounds__(256) void mgemm(
    const bf16* __restrict__ A, const bf16* __restrict__ W,
    const float* __restrict__ bias, const float* R, void* C,
    int N, int K, int Wld)
{
    __shared__ bf16 sA[2][128 * 32];
    __shared__ bf16 sB[2][128 * 32];
    const int t    = threadIdx.x;
    const int lane = t & 63;
    const int wid  = t >> 6;
    const int wr   = wid >> 1, wc = wid & 1;
    const long bm  = (long)blockIdx.x * 128;
    const int  bn  = blockIdx.y * 128;
    const int  fr  = lane & 15;        // frag row/col
    const int  fg  = lane >> 4;        // k-group
    const int  row0 = t >> 2;          // staging row (0..63), +64 for 2nd issue
    const int  kq0  = (t & 3) << 3;    // staging k offset (elems)

    f32x4 acc[4][4];
#pragma unroll
    for (int m = 0; m < 4; ++m)
#pragma unroll
        for (int n = 0; n < 4; ++n)
#pragma unroll
            for (int r = 0; r < 4; ++r) acc[m][n][r] = 0.f;

    const int nkt = K >> 5;

    auto stage = [&](int buf, int kt) {
        const int k0 = kt << 5;
        GLOAD16(A + (bm + row0)      * (long)K   + k0 + kq0, &sA[buf][(t      ) * 8]);
        GLOAD16(A + (bm + row0 + 64) * (long)K   + k0 + kq0, &sA[buf][(t + 256) * 8]);
        GLOAD16(W + (long)(bn + row0)      * Wld + k0 + kq0, &sB[buf][(t      ) * 8]);
        GLOAD16(W + (long)(bn + row0 + 64) * Wld + k0 + kq0, &sB[buf][(t + 256) * 8]);
    };

    stage(0, 0);
    __syncthreads();
    for (int kt = 0; kt < nkt; ++kt) {
        const int cur = kt & 1;
        if (kt + 1 < nkt) stage(cur ^ 1, kt + 1);
        short8 af[4], bg[4];
#pragma unroll
        for (int m = 0; m < 4; ++m)
            af[m] = *(const short8*)&sA[cur][(wr * 64 + m * 16 + fr) * 32 + fg * 8];
#pragma unroll
        for (int n = 0; n < 4; ++n)
            bg[n] = *(const short8*)&sB[cur][(wc * 64 + n * 16 + fr) * 32 + fg * 8];
#pragma unroll
        for (int m = 0; m < 4; ++m)
#pragma unroll
            for (int n = 0; n < 4; ++n)
                acc[m][n] = __builtin_amdgcn_mfma_f32_16x16x32_bf16(
                    af[m], bg[n], acc[m][n], 0, 0, 0);
        __syncthreads();
    }

    // Epilogue. C/D layout (HW-verified): col = lane&15, row = (lane>>4)*4+reg.
    float bs[4];
#pragma unroll
    for (int n = 0; n < 4; ++n) {
        const int c = bn + wc * 64 + n * 16 + fr;
        bs[n] = ((FLAGS & 1) && c < N) ? bias[c] : 0.f;
    }
#pragma unroll
    for (int m = 0; m < 4; ++m) {
#pragma unroll
        for (int n = 0; n < 4; ++n) {
            const int c = bn + wc * 64 + n * 16 + fr;
            if (c < N) {
#pragma unroll
                for (int r = 0; r < 4; ++r) {
                    const long rw = bm + wr * 64 + m * 16 + fg * 4 + r;
                    float v = acc[m][n][r] + bs[n];
                    if (FLAGS & 2) v = fmaxf(v, 0.f);
                    if (FLAGS & 4) v += R[rw * N + c];
                    if (FLAGS & 16) {
                        const int s = (int)(rw >> 5), b = (int)(rw & 31);
                        const int hh = c / 49, cc = c - hh * 49;
                        ((float*)C)[((long)(b * 16 + hh) * 1024 + s) * QSTRIDE + cc] = v;
                    } else if (FLAGS & 8) {
                        ((bf16*)C)[rw * N + c] = __float2bfloat16(v);
                    } else {
                        ((float*)C)[rw * N + c] = v;
                    }
                }
            }
        }
    }
}

// ---------------------------------------------------------------------------
// fp32 -> bf16 bulk convert, count divisible by 8.
// ---------------------------------------------------------------------------
__global__ __launch_bounds__(256) void cvt8(const float* __restrict__ s,
                                            bf16* __restrict__ d, long n8)
{
    for (long i = (long)blockIdx.x * 256 + threadIdx.x; i < n8;
         i += (long)gridDim.x * 256) {
        const float4 a = ((const float4*)s)[i * 2];
        const float4 b = ((const float4*)s)[i * 2 + 1];
        alignas(16) bf16 t[8];
        t[0] = __float2bfloat16(a.x); t[1] = __float2bfloat16(a.y);
        t[2] = __float2bfloat16(a.z); t[3] = __float2bfloat16(a.w);
        t[4] = __float2bfloat16(b.x); t[5] = __float2bfloat16(b.y);
        t[6] = __float2bfloat16(b.z); t[7] = __float2bfloat16(b.w);
        ((short8*)d)[i] = *(const short8*)t;
    }
}

// ---------------------------------------------------------------------------
// fp32 [rows][cols] -> bf16 [prows][pcols], zero-padded.
// ---------------------------------------------------------------------------
__global__ __launch_bounds__(256) void cvtpad(const float* __restrict__ s,
                                              bf16* __restrict__ d,
                                              int rows, int cols, int prows, int pcols)
{
    const long tot = (long)prows * pcols;
    for (long i = (long)blockIdx.x * 256 + threadIdx.x; i < tot;
         i += (long)gridDim.x * 256) {
        const int r = (int)(i / pcols), c = (int)(i - (long)r * pcols);
        d[i] = (r < rows && c < cols) ? __float2bfloat16(s[(long)r * cols + c])
                                      : __float2bfloat16(0.f);
    }
}

// ---------------------------------------------------------------------------
// LayerNorm(256) -> bf16. One wave per row, 4 rows/block.
// ---------------------------------------------------------------------------
__global__ __launch_bounds__(256) void ln_b(
    const float* __restrict__ x, const float* __restrict__ g,
    const float* __restrict__ b, bf16* __restrict__ y)
{
    const int wave = threadIdx.x >> 6, lane = threadIdx.x & 63;
    const long row = (long)(blockIdx.x << 2) + wave;
    const float4 v = ((const float4*)(x + row * HID))[lane];
    float s = v.x + v.y + v.z + v.w;
#pragma unroll
    for (int m = 32; m; m >>= 1) s += __shfl_xor(s, m);
    const float mean = s * (1.f / 256.f);
    const float d0 = v.x - mean, d1 = v.y - mean, d2 = v.z - mean, d3 = v.w - mean;
    float ss = d0 * d0 + d1 * d1 + d2 * d2 + d3 * d3;
#pragma unroll
    for (int m = 32; m; m >>= 1) ss += __shfl_xor(ss, m);
    const float inv = rsqrtf(ss * (1.f / 256.f) + 1e-5f);
    const float4 gg = ((const float4*)g)[lane];
    const float4 bb = ((const float4*)b)[lane];
    alignas(8) bf16 t[4];
    t[0] = __float2bfloat16(fmaf(d0 * inv, gg.x, bb.x));
    t[1] = __float2bfloat16(fmaf(d1 * inv, gg.y, bb.y));
    t[2] = __float2bfloat16(fmaf(d2 * inv, gg.z, bb.z));
    t[3] = __float2bfloat16(fmaf(d3 * inv, gg.w, bb.w));
    *(ushort4*)((unsigned short*)y + row * HID + lane * 4) = *(const ushort4*)t;
}

// ---------------------------------------------------------------------------
// Concat: hcat[row] = [abuf[row] (256 bf16), bf16(emb[fb[row]]) (10), 0 (22)]
// ---------------------------------------------------------------------------
__global__ __launch_bounds__(64) void concat_b(
    const bf16* __restrict__ ab, const float* __restrict__ emb,
    const int* __restrict__ fb, bf16* __restrict__ hcat)
{
    const long row = blockIdx.x;
    const int lane = threadIdx.x;
    const ushort4 v = ((const ushort4*)(ab + row * HID))[lane];
    ((ushort4*)(hcat + row * 288))[lane] = v;
    if (lane < 32) {
        bf16 val = (lane < EMB_D)
            ? __float2bfloat16(emb[(long)fb[row] * EMB_D + lane])
            : __float2bfloat16(0.f);
        hcat[row * 288 + 256 + lane] = val;
    }
}

// 16-element dot of W-column (per-lane regs) with a broadcast row in 4 float4s
#define RED16(dst, M, r0, r1, r2, r3) do {                                     \
    float _ra = fmaf((M)[3],  (r0).w, fmaf((M)[2],  (r0).z, fmaf((M)[1],  (r0).y, (M)[0]  * (r0).x))); \
    float _rb = fmaf((M)[7],  (r1).w, fmaf((M)[6],  (r1).z, fmaf((M)[5],  (r1).y, (M)[4]  * (r1).x))); \
    float _rc = fmaf((M)[11], (r2).w, fmaf((M)[10], (r2).z, fmaf((M)[9],  (r2).y, (M)[8]  * (r2).x))); \
    float _rd = fmaf((M)[15], (r3).w, fmaf((M)[14], (r3).z, fmaf((M)[13], (r3).y, (M)[12] * (r3).x))); \
    dst = (_ra + _rb) + (_rc + _rd);                                           \
} while (0)

// load one step's row (broadcast within chain group; v per-lane)
#define LOADR(S, rowidx) do {                                                  \
    const float* _p = base + (rowidx) * 52;                                    \
    S##k0 = *(const float4*)(_p + 16); S##k1 = *(const float4*)(_p + 20);      \
    S##k2 = *(const float4*)(_p + 24); S##k3 = *(const float4*)(_p + 28);      \
    S##q0 = *(const float4*)(_p +  0); S##q1 = *(const float4*)(_p +  4);      \
    S##q2 = *(const float4*)(_p +  8); S##q3 = *(const float4*)(_p + 12);      \
    S##v  = _p[32 + vi];               S##b  = _p[48];                         \
} while (0)

#define STEP6(S, sg) do {                                                      \
    float _vold; RED16(_vold, W, S##k0, S##k1, S##k2, S##k3);                  \
    const float _dv = S##b * (S##v - _vold);                                   \
    W[0]  = fmaf(S##k0.x, _dv, W[0]);  W[1]  = fmaf(S##k0.y, _dv, W[1]);       \
    W[2]  = fmaf(S##k0.z, _dv, W[2]);  W[3]  = fmaf(S##k0.w, _dv, W[3]);       \
    W[4]  = fmaf(S##k1.x, _dv, W[4]);  W[5]  = fmaf(S##k1.y, _dv, W[5]);       \
    W[6]  = fmaf(S##k1.z, _dv, W[6]);  W[7]  = fmaf(S##k1.w, _dv, W[7]);       \
    W[8]  = fmaf(S##k2.x, _dv, W[8]);  W[9]  = fmaf(S##k2.y, _dv, W[9]);       \
    W[10] = fmaf(S##k2.z, _dv, W[10]); W[11] = fmaf(S##k2.w, _dv, W[11]);      \
    W[12] = fmaf(S##k3.x, _dv, W[12]); W[13] = fmaf(S##k3.y, _dv, W[13]);      \
    W[14] = fmaf(S##k3.z, _dv, W[14]); W[15] = fmaf(S##k3.w, _dv, W[15]);      \
    float _ov; RED16(_ov, W, S##q0, S##q1, S##q2, S##q3);                      \
    po[(long)(sg) * (B_SZ * HID)] = __float2bfloat16(_ov);                     \
} while (0)

// ---------------------------------------------------------------------------
// Delta-rule scan v6: scan3 math + branch-free 2-deep A/B register ping-pong +
// __launch_bounds__(64,1) so the allocator keeps the pipeline in VGPRs
// (blocks are single-wave; occupancy is 1 wave/CU regardless, VGPRs are free).
// Tail prefetches read a padded LDS region (never consumed) to stay
// branch-free. Chunks double-buffered via global_load_lds + counted vmcnt.
// ---------------------------------------------------------------------------
__global__ __launch_bounds__(64, 1) void scan6(
    const float* __restrict__ qkvb, bf16* __restrict__ o)
{
    __shared__ float lds[2 * BUFF + 224];      // +224 floats: tail-prefetch pad
    const int lane = threadIdx.x;
    const int c  = lane >> 4;        // chain within block
    const int vi = lane & 15;        // v column
    const int bh0 = blockIdx.x << 2; // 4 chains per block
    const int chain = bh0 + c;
    const int b = chain >> 4, hh = chain & 15;

    bf16* po = o + (long)b * HID + hh * HDIM + vi;

    // stage chunk ch into lds[buf*BUFF]: 26 issues x 64 lanes x 16B
    auto stage = [&](int buf, int ch) {
#pragma unroll
        for (int i = 0; i < 26; ++i) {
            const int slot = i * 64 + lane;        // float4 slot in LDS
            const int row  = slot / 13;            // 0..127 = s_local*4 + cc
            const int f4   = slot - row * 13;
            const int cc   = row & 3, sl = row >> 2;
            const float* src = qkvb
                + (((long)(bh0 + cc) << 10) + ch * CHUNK + sl) * QSTRIDE + f4 * 4;
            GLOAD16(src, &lds[buf * BUFF + i * 256]);
        }
    };

    float W[16];
#pragma unroll
    for (int j = 0; j < 16; ++j) W[j] = 0.f;

    stage(0, 0);
    asm volatile("s_waitcnt vmcnt(0)" ::: "memory");
    const int nch = S_LEN / CHUNK;
    for (int ch = 0; ch < nch; ++ch) {
        const int buf = ch & 1;
        // chunk ch's 26 loads are older than the <=32 newest output stores.
        asm volatile("s_waitcnt vmcnt(32)" ::: "memory");
        if (ch + 1 < nch) stage(buf ^ 1, ch + 1);   // lands during prep+rec

        float* base = lds + buf * BUFF;
        // ---- fused prep: softmax q[0:16], k[16:32], sigmoid beta[48] ----
#pragma unroll
        for (int rr = 0; rr < 2; ++rr) {
            float* p = base + (rr * 64 + lane) * 52;
            float4 q[4], k[4];
#pragma unroll
            for (int i = 0; i < 4; ++i) {
                q[i] = *(float4*)(p + i * 4);
                k[i] = *(float4*)(p + 16 + i * 4);
            }
            float qm = -1e30f, km = -1e30f;
#pragma unroll
            for (int i = 0; i < 4; ++i) {
                qm = fmaxf(qm, fmaxf(fmaxf(q[i].x, q[i].y), fmaxf(q[i].z, q[i].w)));
                km = fmaxf(km, fmaxf(fmaxf(k[i].x, k[i].y), fmaxf(k[i].z, k[i].w)));
            }
            float qs = 0.f, ks = 0.f;
#pragma unroll
            for (int i = 0; i < 4; ++i) {
                q[i].x = __expf(q[i].x - qm); q[i].y = __expf(q[i].y - qm);
                q[i].z = __expf(q[i].z - qm); q[i].w = __expf(q[i].w - qm);
                qs += q[i].x + q[i].y + q[i].z + q[i].w;
                k[i].x = __expf(k[i].x - km); k[i].y = __expf(k[i].y - km);
                k[i].z = __expf(k[i].z - km); k[i].w = __expf(k[i].w - km);
                ks += k[i].x + k[i].y + k[i].z + k[i].w;
            }
            const float qi = 1.f / qs, ki = 1.f / ks;
#pragma unroll
            for (int i = 0; i < 4; ++i) {
                q[i].x *= qi; q[i].y *= qi; q[i].z *= qi; q[i].w *= qi;
                k[i].x *= ki; k[i].y *= ki; k[i].z *= ki; k[i].w *= ki;
                *(float4*)(p + i * 4) = q[i];
                *(float4*)(p + 16 + i * 4) = k[i];
            }
            p[48] = 1.f / (1.f + __expf(-p[48]));
        }
        asm volatile("s_waitcnt lgkmcnt(0)" ::: "memory"); // prep visible wave-wide

        // ---- recurrence: branch-free 2-deep A/B ping-pong ----
        const int sg0 = ch * CHUNK;
        float4 Ak0, Ak1, Ak2, Ak3, Aq0, Aq1, Aq2, Aq3;
        float4 Bk0, Bk1, Bk2, Bk3, Bq0, Bq1, Bq2, Bq3;
        float Av, Ab, Bv, Bb;
        LOADR(A, c);
#pragma unroll
        for (int sl = 0; sl < CHUNK; sl += 2) {
            LOADR(B, (sl + 1) * 4 + c);            // prefetch next step
            STEP6(A, sg0 + sl);
            LOADR(A, (sl + 2) * 4 + c);            // tail hits pad region only
            STEP6(B, sg0 + sl + 1);
        }
    }
}

// ---------------------------------------------------------------------------
extern "C" void kernel_launch(void* const* d_in, const int* in_sizes, int n_in,
                              void* d_out, int out_size, void* d_ws, size_t ws_size,
                              hipStream_t stream)
{
    const float* x      = (const float*)d_in[0];
    const int*   fb     = (const int*)  d_in[1];
    const float* fc1_w  = (const float*)d_in[2];
    const float* fc1_b  = (const float*)d_in[3];
    const float* emb    = (const float*)d_in[4];
    const float* proj_w = (const float*)d_in[5];
    const float* proj_b = (const float*)d_in[6];
    const float* ln1_g  = (const float*)d_in[7];
    const float* ln1_b  = (const float*)d_in[8];
    const float* slow_w = (const float*)d_in[9];
    const float* out_w  = (const float*)d_in[10];
    const float* ln2_g  = (const float*)d_in[11];
    const float* ln2_b  = (const float*)d_in[12];
    const float* ff1_w  = (const float*)d_in[13];
    const float* ff1_b  = (const float*)d_in[14];
    const float* ff2_w  = (const float*)d_in[15];
    const float* ff2_b  = (const float*)d_in[16];
    const float* outl_w = (const float*)d_in[17];
    const float* outl_b = (const float*)d_in[18];

    // ---- workspace layout (59.5 MB) ----
    char* wp = (char*)d_ws;
    float* h    = (float*)wp;                 wp += (size_t)MROWS * HID * 4;   // 33.5MB
    bf16*  abuf = (bf16*)wp;                  wp += (size_t)MROWS * HID * 2;   // 16.8MB
    bf16*  fc1b = (bf16*)wp;                  wp += (size_t)HID * IN_DIM * 2;
    bf16*  projb= (bf16*)wp;                  wp += (size_t)HID * 288 * 2;
    bf16*  slowb= (bf16*)wp;                  wp += (size_t)NLAYER * 896 * HID * 2;
    bf16*  outwb= (bf16*)wp;                  wp += (size_t)NLAYER * HID * HID * 2;
    bf16*  ff1b = (bf16*)wp;                  wp += (size_t)NLAYER * DFF * HID * 2;
    bf16*  ff2b = (bf16*)wp;                  wp += (size_t)NLAYER * HID * DFF * 2;
    bf16*  outlb= (bf16*)wp;                  wp += (size_t)1664 * HID * 2;

    // ---- d_out scratch (212.9 MB), sequentially reused ----
    bf16*  xb   = (bf16*)d_out;               // 201.3MB, dead after fc1
    bf16*  hcat = (bf16*)d_out;               // 18.9MB, dead after proj
    float* qkvb = (float*)d_out;              // 109.1MB, dead after scan
    bf16*  hff  = (bf16*)d_out;               // 67.1MB, dead after ff2

    const dim3 blk(256);

    // ---- weight/input conversions (re-done every launch; deterministic) ----
    cvt8<<<dim3(4096), blk, 0, stream>>>(x, xb, (long)MROWS * IN_DIM / 8);
    cvt8<<<dim3(384),  blk, 0, stream>>>(fc1_w, fc1b, (long)HID * IN_DIM / 8);
    cvtpad<<<dim3(288), blk, 0, stream>>>(proj_w, projb, HID, HID + EMB_D, HID, 288);
    for (int l = 0; l < NLAYER; ++l)
        cvtpad<<<dim3(896), blk, 0, stream>>>(slow_w + (size_t)l * 784 * HID,
                                              slowb + (size_t)l * 896 * HID,
                                              784, HID, 896, HID);
    cvt8<<<dim3(128), blk, 0, stream>>>(out_w, outwb, (long)NLAYER * HID * HID / 8);
    cvt8<<<dim3(512), blk, 0, stream>>>(ff1_w, ff1b, (long)NLAYER * DFF * HID / 8);
    cvt8<<<dim3(512), blk, 0, stream>>>(ff2_w, ff2b, (long)NLAYER * HID * DFF / 8);
    cvtpad<<<dim3(1664), blk, 0, stream>>>(outl_w, outlb, NCLS, HID, 1664, HID);

    // fc1: abuf = bf16(x @ fc1_w^T + b)    N=256 K=3072
    mgemm<9><<<dim3(256, 2), blk, 0, stream>>>(xb, fc1b, fc1_b, nullptr, abuf,
                                               HID, IN_DIM, IN_DIM);
    // hcat = [abuf, emb[fb], 0-pad]  (K padded to 288)
    concat_b<<<dim3(MROWS), dim3(64), 0, stream>>>(abuf, emb, fb, hcat);
    // proj: h = hcat @ proj_w^T + b        N=256 K=288(266+pad)
    mgemm<1><<<dim3(256, 2), blk, 0, stream>>>(hcat, projb, proj_b, nullptr, h,
                                               HID, 288, 288);

    for (int l = 0; l < NLAYER; ++l) {
        ln_b<<<dim3(MROWS / 4), blk, 0, stream>>>(h, ln1_g + l * HID, ln1_b + l * HID, abuf);
        // qkvb (permuted (b,h,s,52) fp32, RAW — softmax fused into scan6)
        mgemm<16><<<dim3(256, 7), blk, 0, stream>>>(abuf, slowb + (size_t)l * 896 * HID,
                                                    nullptr, nullptr, qkvb, 784, HID, HID);
        scan6<<<dim3(B_SZ * NHEAD / 4), dim3(64), 0, stream>>>(qkvb, abuf);
        // h += o @ out_w^T                  N=256 K=256
        mgemm<4><<<dim3(256, 2), blk, 0, stream>>>(abuf, outwb + (size_t)l * HID * HID,
                                                   nullptr, h, h, HID, HID, HID);
        ln_b<<<dim3(MROWS / 4), blk, 0, stream>>>(h, ln2_g + l * HID, ln2_b + l * HID, abuf);
        // hff = bf16(relu(y @ ff1^T + b1))  N=1024 K=256
        mgemm<11><<<dim3(256, 8), blk, 0, stream>>>(abuf, ff1b + (size_t)l * DFF * HID,
                                                    ff1_b + l * DFF, nullptr, hff,
                                                    DFF, HID, HID);
        // h += hff @ ff2^T + b2             N=256 K=1024
        mgemm<5><<<dim3(256, 2), blk, 0, stream>>>(hff, ff2b + (size_t)l * HID * DFF,
                                                   ff2_b + l * HID, h, h, HID, DFF, DFF);
    }
    // final: abuf = bf16(h); out = abuf @ outl_w^T + b  (fp32, N=1623 K=256)
    cvt8<<<dim3(1024), blk, 0, stream>>>(h, abuf, (long)MROWS * HID / 8);
    mgemm<1><<<dim3(256, 13), blk, 0, stream>>>(abuf, outlb, outl_b, nullptr, d_out,
                                                NCLS, HID, HID);
}